// Round 15
// baseline (92.365 us; speedup 1.0000x reference)
//
#include <hip/hip_runtime.h>
#include <hip/hip_bf16.h>

// MultiEdgeTypePredictor — R12: R11 + balanced grid-stride proj (no dispatch tail).
//
//   Psrc = h_src @ W1[:256,:] ; Pdst = h_dst @ W1[256:,:] + b1   (bf16, d_ws)
//   x[e] = relu(Psrc[s[e]] + Pdst[d[e]]) * sc + sh ; GEMM2 ; GEMM3
//
//   R11 measured proj at 54% occupancy: grid 3126 > ~2048 co-resident blocks
//   -> 1.5-block-wave dispatch tail ran half-empty. R12 launches 1563 blocks,
//   each doing exactly 2 tiles (b: src half, b+1563: dst half) — all blocks
//   co-resident, identical work, latency covered by cross-block overlap.

typedef __attribute__((ext_vector_type(8))) short bf16x8;
typedef __attribute__((ext_vector_type(4))) float f32x4;
typedef __attribute__((ext_vector_type(8))) unsigned short u16x8;

constexpr int HID   = 128;
constexpr int ETILE = 64;
constexpr int AS    = 72;    // fallback chunk stride (bf16 elems)
constexpr int XS    = 136;   // tile row stride (bf16 elems, 272B)

__device__ inline ushort f2bf(float f) {
    union { __hip_bfloat16 h; ushort u; } cv;
    cv.h = __float2bfloat16(f);   // RNE
    return cv.u;
}
__device__ inline float bf2f(ushort u) {
    return __uint_as_float(((unsigned int)u) << 16);
}

// ---------------- prep: pack weights + fold BN/emb ----------------
__global__ __launch_bounds__(256)
void prep_kernel(const float* __restrict__ W1, const float* __restrict__ W2,
                 const float* __restrict__ bn_gamma, const float* __restrict__ bn_beta,
                 const float* __restrict__ bn_mean, const float* __restrict__ bn_var,
                 const float* __restrict__ emb, const int* __restrict__ etype,
                 ushort* __restrict__ B1p, ushort* __restrict__ B2p,
                 float* __restrict__ sc, float* __restrict__ sh)
{
    int i = blockIdx.x * blockDim.x + threadIdx.x;
    if (i < 65536) {
        // B1 frag: i = ((ks*8 + ct)*64 + lane)*8 + j ; k = ks*32+(lane>>4)*8+j ; c = ct*16+(lane&15)
        int j = i & 7, lane = (i >> 3) & 63, ct = (i >> 9) & 7, ks = i >> 12;
        int k = ks * 32 + (lane >> 4) * 8 + j;
        int c = ct * 16 + (lane & 15);
        B1p[i] = f2bf(W1[k * HID + c]);
    } else if (i < 65536 + 8192) {
        int p = i - 65536;
        int j = p & 7, lane = (p >> 3) & 63, ct = (p >> 9) & 3, ks = p >> 11;
        int k = ks * 32 + (lane >> 4) * 8 + j;
        int c = ct * 16 + (lane & 15);
        B2p[p] = f2bf(W2[k * 64 + c]);
    } else if (i < 65536 + 8192 + HID) {
        int c = i - 65536 - 8192;
        float s = bn_gamma[c] * rsqrtf(bn_var[c] + 1e-5f);
        sc[c] = s;
        sh[c] = bn_beta[c] - bn_mean[c] * s + emb[etype[0] * HID + c];
    }
}

// ---------------- proj: P = h @ W1_half (+b1 on dst half) ----------------
// grid = ntiles blocks; block b processes tile b (src half) and b+ntiles (dst).
__global__ __launch_bounds__(256)
void proj_kernel(const float* __restrict__ h_src, const float* __restrict__ h_dst,
                 const ushort* __restrict__ B1p, const float* __restrict__ b1,
                 ushort* __restrict__ Psrc, ushort* __restrict__ Pdst,
                 int n_nodes, int ntiles)
{
    __shared__ ushort sA[ETILE * XS];     // 64 x 136 bf16 = 17408 B (A-chunk / X-tile)

    const int t    = threadIdx.x;
    const int lane = t & 63;
    const int w    = t >> 6;
    const int lr   = lane & 15;
    const int lq   = lane >> 4;

#pragma unroll 1
    for (int half = 0; half < 2; ++half) {
        const float* hp = half ? h_dst : h_src;
        ushort* Pp      = half ? Pdst : Psrc;
        const int nb    = blockIdx.x * 64;

        f32x4 acc[4][2];
#pragma unroll
        for (int rt = 0; rt < 4; ++rt)
#pragma unroll
            for (int c = 0; c < 2; ++c) acc[rt][c] = (f32x4)0.0f;

        // K = 256 in 2 chunks of 128
        for (int kc = 0; kc < 2; ++kc) {
            const int koff = kc * 128;
            __syncthreads();   // previous readers done (also covers prev tile's P store)

            // stage 64 rows x 128 cols: 2048 float4, coalesced, fp32 -> bf16
#pragma unroll
            for (int i = 0; i < 8; ++i) {
                int f = t + i * 256;
                int e = f >> 5, q = f & 31;
                int row = nb + e;
                if (row >= n_nodes) row = n_nodes - 1;   // tail clamp (stores guarded)
                float4 v = *reinterpret_cast<const float4*>(
                    hp + (size_t)row * 256 + koff + q * 4);
                ushort4 bv;
                bv.x = f2bf(v.x); bv.y = f2bf(v.y); bv.z = f2bf(v.z); bv.w = f2bf(v.w);
                *reinterpret_cast<ushort4*>(&sA[e * XS + q * 4]) = bv;
            }
            __syncthreads();

#pragma unroll
            for (int ks = 0; ks < 4; ++ks) {
                const int kstep = half * 8 + kc * 4 + ks;
                bf16x8 bf0 = *reinterpret_cast<const bf16x8*>(
                    B1p + (size_t)((kstep * 8 + 2 * w) * 64 + lane) * 8);
                bf16x8 bf1 = *reinterpret_cast<const bf16x8*>(
                    B1p + (size_t)((kstep * 8 + 2 * w + 1) * 64 + lane) * 8);
#pragma unroll
                for (int rt = 0; rt < 4; ++rt) {
                    bf16x8 af = *reinterpret_cast<const bf16x8*>(
                        &sA[(rt * 16 + lr) * XS + ks * 32 + lq * 8]);
                    acc[rt][0] = __builtin_amdgcn_mfma_f32_16x16x32_bf16(af, bf0, acc[rt][0], 0, 0, 0);
                    acc[rt][1] = __builtin_amdgcn_mfma_f32_16x16x32_bf16(af, bf1, acc[rt][1], 0, 0, 0);
                }
            }
        }

        __syncthreads();   // all A readers done before X-tile overwrite

        // epilogue: fold b1 into the dst half; acc -> LDS bf16 tile
#pragma unroll
        for (int ctl = 0; ctl < 2; ++ctl) {
            int c = (2 * w + ctl) * 16 + lr;
            float add = half ? b1[c] : 0.0f;
#pragma unroll
            for (int rt = 0; rt < 4; ++rt)
#pragma unroll
                for (int r = 0; r < 4; ++r)
                    sA[(rt * 16 + lq * 4 + r) * XS + c] = f2bf(acc[rt][ctl][r] + add);
        }
        __syncthreads();

        // cooperative coalesced store to P
#pragma unroll
        for (int i = 0; i < 4; ++i) {
            int f = t + i * 256;
            int e = f >> 4, q = f & 15;
            if (nb + e < n_nodes) {
                u16x8 v = *reinterpret_cast<const u16x8*>(&sA[e * XS + q * 8]);
                *reinterpret_cast<u16x8*>(Pp + (size_t)(nb + e) * 128 + q * 8) = v;
            }
        }
    }
}

// ---------------- edge: coalesced gather + fuse + GEMM2/3 ----------------
__global__ __launch_bounds__(256)
void edge_kernel(const ushort* __restrict__ Psrc, const ushort* __restrict__ Pdst,
                 const int* __restrict__ src_nodes, const int* __restrict__ dst_nodes,
                 const float* __restrict__ sc, const float* __restrict__ sh,
                 const float* __restrict__ b2, const float* __restrict__ W3,
                 const float* __restrict__ b3, const ushort* __restrict__ B2p,
                 float* __restrict__ out, int n_edges)
{
    __shared__ ushort sX[ETILE * XS];
    __shared__ int s_s[ETILE], s_d[ETILE];

    const int t     = threadIdx.x;
    const int lane  = t & 63;
    const int w     = t >> 6;
    const int lr    = lane & 15;
    const int lq    = lane >> 4;
    const int ebase = blockIdx.x * ETILE;

    if (t < ETILE) {
        int e = ebase + t;
        s_s[t] = src_nodes[e < n_edges ? e : (n_edges - 1)];
    } else if (t < 2 * ETILE) {
        int e = ebase + t - ETILE;
        s_d[t - ETILE] = dst_nodes[e < n_edges ? e : (n_edges - 1)];
    }
    __syncthreads();

    // gather: 16 lanes per P row (256B contiguous segments)
    const int eg = w * 16 + lq;      // local edge group base
    const int ch = lr;               // 16B chunk within row
    u16x8 gs[4], gd[4];
#pragma unroll
    for (int j = 0; j < 4; ++j)
        gs[j] = *reinterpret_cast<const u16x8*>(
            Psrc + (size_t)s_s[eg + j * 4] * 128 + ch * 8);
#pragma unroll
    for (int j = 0; j < 4; ++j)
        gd[j] = *reinterpret_cast<const u16x8*>(
            Pdst + (size_t)s_d[eg + j * 4] * 128 + ch * 8);
    asm volatile("" :: "v"(gs[0]), "v"(gs[1]), "v"(gs[2]), "v"(gs[3]),
                       "v"(gd[0]), "v"(gd[1]), "v"(gd[2]), "v"(gd[3]));

    // decode: relu(a+b) * sc + sh -> x (bf16) in LDS
    const int c0 = ch * 8;
    float4 sca = *reinterpret_cast<const float4*>(sc + c0);
    float4 scb = *reinterpret_cast<const float4*>(sc + c0 + 4);
    float4 sha = *reinterpret_cast<const float4*>(sh + c0);
    float4 shb = *reinterpret_cast<const float4*>(sh + c0 + 4);
    float ss[8] = {sca.x, sca.y, sca.z, sca.w, scb.x, scb.y, scb.z, scb.w};
    float zz[8] = {sha.x, sha.y, sha.z, sha.w, shb.x, shb.y, shb.z, shb.w};
#pragma unroll
    for (int j = 0; j < 4; ++j) {
        u16x8 xo;
#pragma unroll
        for (int i = 0; i < 8; ++i) {
            float v = bf2f((ushort)gs[j][i]) + bf2f((ushort)gd[j][i]);
            v = fmaxf(v, 0.0f);
            xo[i] = f2bf(fmaf(v, ss[i], zz[i]));
        }
        *reinterpret_cast<u16x8*>(&sX[(eg + j * 4) * XS + c0]) = xo;
    }
    __syncthreads();

    // -------- GEMM2 --------
    f32x4 acc2[4];
#pragma unroll
    for (int ct = 0; ct < 4; ++ct) acc2[ct] = (f32x4)0.0f;

#pragma unroll
    for (int ks = 0; ks < 4; ++ks) {
        bf16x8 af = *reinterpret_cast<const bf16x8*>(
            &sX[(w * 16 + lr) * XS + ks * 32 + lq * 8]);
#pragma unroll
        for (int ct = 0; ct < 4; ++ct) {
            bf16x8 bf = *reinterpret_cast<const bf16x8*>(
                B2p + (size_t)((ks * 4 + ct) * 64 + lane) * 8);
            acc2[ct] = __builtin_amdgcn_mfma_f32_16x16x32_bf16(af, bf, acc2[ct], 0, 0, 0);
        }
    }

    // -------- GEMM3 --------
    float w3v[4], b2v[4];
#pragma unroll
    for (int ct = 0; ct < 4; ++ct) {
        int c = ct * 16 + lr;
        w3v[ct] = W3[c];
        b2v[ct] = b2[c];
    }
#pragma unroll
    for (int r = 0; r < 4; ++r) {
        float sum = 0.0f;
#pragma unroll
        for (int ct = 0; ct < 4; ++ct)
            sum += fmaxf(acc2[ct][r] + b2v[ct], 0.0f) * w3v[ct];
        sum += __shfl_xor(sum, 1);
        sum += __shfl_xor(sum, 2);
        sum += __shfl_xor(sum, 4);
        sum += __shfl_xor(sum, 8);
        int eo = ebase + w * 16 + lq * 4 + r;
        if (lr == 0 && eo < n_edges) out[eo] = sum + b3[0];
    }
}

// ================= fallback: R10 champion fused path (97.7us) =================
__global__ __launch_bounds__(256, 3)
void edge_mlp_mfma(const float* __restrict__ h_src, const float* __restrict__ h_dst,
                   const int* __restrict__ src_nodes, const int* __restrict__ dst_nodes,
                   const ushort* __restrict__ B1p, const ushort* __restrict__ B2p,
                   const float* __restrict__ b1, const float* __restrict__ sc,
                   const float* __restrict__ sh, const float* __restrict__ b2,
                   const float* __restrict__ W3, const float* __restrict__ b3,
                   float* __restrict__ out, int n_edges)
{
    __shared__ ushort sA[2][ETILE * AS];
    __shared__ int s_src[ETILE], s_dst[ETILE];

    const int t    = threadIdx.x;
    const int lane = t & 63;
    const int w    = t >> 6;
    const int lr   = lane & 15;
    const int lq   = lane >> 4;
    const int ebase = blockIdx.x * ETILE;

    if (t < ETILE) {
        int e = ebase + t;
        s_src[t] = src_nodes[e < n_edges ? e : 0];
    } else if (t < 2 * ETILE) {
        int e = ebase + t - ETILE;
        s_dst[t - ETILE] = dst_nodes[e < n_edges ? e : 0];
    }

    f32x4 acc[4][2];
#pragma unroll
    for (int rt = 0; rt < 4; ++rt)
#pragma unroll
        for (int c = 0; c < 2; ++c) acc[rt][c] = (f32x4)0.0f;

    float4 rA[4], rB[4];
    bf16x8 Bf0[4], Bf1[4];

#define PHASE_BAR() do {                                                       \
        asm volatile("s_waitcnt lgkmcnt(0)" ::: "memory");                     \
        __builtin_amdgcn_s_barrier();                                          \
    } while (0)
#define PIN() __builtin_amdgcn_sched_barrier(0)

#define LOADC(kc, R) do {                                                      \
        const float* hp = ((kc) < 4) ? h_src : h_dst;                          \
        const int* sidx = ((kc) < 4) ? s_src : s_dst;                          \
        const int koff = ((kc) & 3) * 64;                                      \
        _Pragma("unroll")                                                      \
        for (int i = 0; i < 4; ++i) {                                          \
            int f = t + i * 256; int e = f >> 4; int q = f & 15;               \
            R[i] = *reinterpret_cast<const float4*>(                           \
                hp + (size_t)sidx[e] * 256 + koff + q * 4);                    \
        } } while (0)

#define BLOAD(kc, BR) do {                                                     \
        _Pragma("unroll")                                                      \
        for (int s = 0; s < 2; ++s)                                            \
        _Pragma("unroll")                                                      \
        for (int c = 0; c < 2; ++c)                                            \
            BR[s * 2 + c] = *reinterpret_cast<const bf16x8*>(                  \
                B1p + (size_t)((((kc) * 2 + s) * 8 + 2 * w + c) * 64 + lane) * 8); \
        } while (0)

#define STOREC(B, R) do {                                                      \
        _Pragma("unroll")                                                      \
        for (int i = 0; i < 4; ++i) {                                          \
            int f = t + i * 256; int e = f >> 4; int q = f & 15;               \
            ushort4 bv;                                                        \
            bv.x = f2bf(R[i].x); bv.y = f2bf(R[i].y);                          \
            bv.z = f2bf(R[i].z); bv.w = f2bf(R[i].w);                          \
            *reinterpret_cast<ushort4*>(&sA[B][e * AS + q * 4]) = bv;          \
        } } while (0)

#define COMPF(B, BR) do {                                                      \
        _Pragma("unroll")                                                      \
        for (int ks = 0; ks < 2; ++ks) {                                       \
            _Pragma("unroll")                                                  \
            for (int rt = 0; rt < 4; ++rt) {                                   \
                bf16x8 af = *reinterpret_cast<const bf16x8*>(                  \
                    &sA[B][(rt * 16 + lr) * AS + ks * 32 + lq * 8]);           \
                acc[rt][0] = __builtin_amdgcn_mfma_f32_16x16x32_bf16(af, BR[ks * 2 + 0], acc[rt][0], 0, 0, 0); \
                acc[rt][1] = __builtin_amdgcn_mfma_f32_16x16x32_bf16(af, BR[ks * 2 + 1], acc[rt][1], 0, 0, 0); \
            } } } while (0)

    __syncthreads();

    LOADC(0, rA);
    BLOAD(0, Bf0);
    STOREC(0, rA);
    LOADC(1, rB);
    BLOAD(1, Bf1);
    PHASE_BAR();

    LOADC(2, rA);  PIN();  COMPF(0, Bf0);  BLOAD(2, Bf0);  STOREC(1, rB);  PHASE_BAR();
    LOADC(3, rB);  PIN();  COMPF(1, Bf1);  BLOAD(3, Bf1);  STOREC(0, rA);  PHASE_BAR();
    LOADC(4, rA);  PIN();  COMPF(0, Bf0);  BLOAD(4, Bf0);  STOREC(1, rB);  PHASE_BAR();
    LOADC(5, rB);  PIN();  COMPF(1, Bf1);  BLOAD(5, Bf1);  STOREC(0, rA);  PHASE_BAR();
    LOADC(6, rA);  PIN();  COMPF(0, Bf0);  BLOAD(6, Bf0);  STOREC(1, rB);  PHASE_BAR();
    LOADC(7, rB);  PIN();  COMPF(1, Bf1);  BLOAD(7, Bf1);  STOREC(0, rA);  PHASE_BAR();
                           COMPF(0, Bf0);                  STOREC(1, rB);  PHASE_BAR();
                           COMPF(1, Bf1);

#undef LOADC
#undef BLOAD
#undef STOREC
#undef COMPF
#undef PIN
#undef PHASE_BAR

    __syncthreads();
    ushort* sX = &sA[0][0];
#pragma unroll
    for (int ctl = 0; ctl < 2; ++ctl) {
        int c = (2 * w + ctl) * 16 + lr;
        float bb = b1[c], s = sc[c], z = sh[c];
#pragma unroll
        for (int rt = 0; rt < 4; ++rt)
#pragma unroll
            for (int r = 0; r < 4; ++r) {
                float x = fmaxf(acc[rt][ctl][r] + bb, 0.0f);
                sX[(rt * 16 + lq * 4 + r) * XS + c] = f2bf(fmaf(x, s, z));
            }
    }
    __syncthreads();

    f32x4 acc2[4];
#pragma unroll
    for (int ct = 0; ct < 4; ++ct) acc2[ct] = (f32x4)0.0f;

#pragma unroll
    for (int ks = 0; ks < 4; ++ks) {
        bf16x8 af = *reinterpret_cast<const bf16x8*>(
            &sX[(w * 16 + lr) * XS + ks * 32 + lq * 8]);
#pragma unroll
        for (int ct = 0; ct < 4; ++ct) {
            bf16x8 bf = *reinterpret_cast<const bf16x8*>(
                B2p + (size_t)((ks * 4 + ct) * 64 + lane) * 8);
            acc2[ct] = __builtin_amdgcn_mfma_f32_16x16x32_bf16(af, bf, acc2[ct], 0, 0, 0);
        }
    }

    float w3v[4], b2v[4];
#pragma unroll
    for (int ct = 0; ct < 4; ++ct) {
        int c = ct * 16 + lr;
        w3v[ct] = W3[c];
        b2v[ct] = b2[c];
    }
#pragma unroll
    for (int r = 0; r < 4; ++r) {
        float sum = 0.0f;
#pragma unroll
        for (int ct = 0; ct < 4; ++ct)
            sum += fmaxf(acc2[ct][r] + b2v[ct], 0.0f) * w3v[ct];
        sum += __shfl_xor(sum, 1);
        sum += __shfl_xor(sum, 2);
        sum += __shfl_xor(sum, 4);
        sum += __shfl_xor(sum, 8);
        int e = ebase + w * 16 + lq * 4 + r;
        if (lr == 0 && e < n_edges) out[e] = sum + b3[0];
    }
}

extern "C" void kernel_launch(void* const* d_in, const int* in_sizes, int n_in,
                              void* d_out, int out_size, void* d_ws, size_t ws_size,
                              hipStream_t stream) {
    const float* h_src     = (const float*)d_in[0];
    const float* h_dst     = (const float*)d_in[1];
    const int*   src_nodes = (const int*)d_in[2];
    const int*   dst_nodes = (const int*)d_in[3];
    const int*   etype     = (const int*)d_in[4];
    const float* W1        = (const float*)d_in[5];
    const float* b1        = (const float*)d_in[6];
    const float* bn_gamma  = (const float*)d_in[7];
    const float* bn_beta   = (const float*)d_in[8];
    const float* bn_mean   = (const float*)d_in[9];
    const float* bn_var    = (const float*)d_in[10];
    const float* emb       = (const float*)d_in[11];
    const float* W2        = (const float*)d_in[12];
    const float* b2        = (const float*)d_in[13];
    const float* W3        = (const float*)d_in[14];
    const float* b3        = (const float*)d_in[15];

    const int n_edges = in_sizes[2];
    const int n_nodes = in_sizes[0] / 256;

    // d_ws layout: B1p[65536 u16] | B2p[8192 u16] | sc[128] | sh[128] | Psrc | Pdst
    ushort* B1p = (ushort*)d_ws;
    ushort* B2p = B1p + 65536;
    float*  scp = (float*)(B2p + 8192);
    float*  shp = scp + HID;
    const size_t wbytes = (size_t)(65536 + 8192) * 2 + 256 * 4;   // 148480 B
    const size_t pbytes = (size_t)n_nodes * HID * 2;              // per P array
    ushort* Psrc = (ushort*)((char*)d_ws + wbytes);
    ushort* Pdst = Psrc + (size_t)n_nodes * HID;

    prep_kernel<<<(65536 + 8192 + HID + 255) / 256, 256, 0, stream>>>(
        W1, W2, bn_gamma, bn_beta, bn_mean, bn_var, emb, etype, B1p, B2p, scp, shp);

    const int egrid = (n_edges + ETILE - 1) / ETILE;

    if (ws_size >= wbytes + 2 * pbytes) {
        const int ntiles = (n_nodes + 63) / 64;
        proj_kernel<<<ntiles, 256, 0, stream>>>(h_src, h_dst, B1p, b1,
                                                Psrc, Pdst, n_nodes, ntiles);
        edge_kernel<<<egrid, 256, 0, stream>>>(Psrc, Pdst, src_nodes, dst_nodes,
                                               scp, shp, b2, W3, b3, B2p,
                                               (float*)d_out, n_edges);
    } else {
        edge_mlp_mfma<<<egrid, 256, 0, stream>>>(h_src, h_dst, src_nodes, dst_nodes,
                                                 B1p, B2p, b1, scp, shp, b2, W3, b3,
                                                 (float*)d_out, n_edges);
    }
}

// Round 16
// 87.425 us; speedup vs baseline: 1.0565x; 1.0565x over previous
//
#include <hip/hip_runtime.h>
#include <hip/hip_bf16.h>

// MultiEdgeTypePredictor — R13: proj v3 (B-frags in registers, full-K stage,
// exact-balance multi-tile blocks).
//
//   Psrc = h_src @ W1[:256,:] ; Pdst = h_dst @ W1[256:,:] + b1   (bf16, d_ws)
//   x[e] = relu(Psrc[s[e]] + Pdst[d[e]]) * sc + sh ; GEMM2 ; GEMM3
//
//   R12 post-mortem: proj's limiter was the 16 per-tile B-fragment GLOBAL
//   loads (L2 ~250cy each) serially interleaved with MFMA — not dispatch
//   shape. R13: B-frags loaded ONCE per half into 64 VGPRs (loop-invariant,
//   statically indexed), full-K=256 stage per tile (16 loads/thread in
//   flight), 521 blocks x 3 tiles/half exact balance.

typedef __attribute__((ext_vector_type(8))) short bf16x8;
typedef __attribute__((ext_vector_type(4))) float f32x4;
typedef __attribute__((ext_vector_type(8))) unsigned short u16x8;

constexpr int HID   = 128;
constexpr int ETILE = 64;
constexpr int AS    = 72;    // fallback chunk stride (bf16 elems)
constexpr int XS    = 136;   // edge x-tile row stride (bf16 elems, 272B)
constexpr int PS    = 264;   // proj A-tile row stride (bf16 elems, 528B)

__device__ inline ushort f2bf(float f) {
    union { __hip_bfloat16 h; ushort u; } cv;
    cv.h = __float2bfloat16(f);   // RNE
    return cv.u;
}
__device__ inline float bf2f(ushort u) {
    return __uint_as_float(((unsigned int)u) << 16);
}

// ---------------- prep: pack weights + fold BN/emb ----------------
__global__ __launch_bounds__(256)
void prep_kernel(const float* __restrict__ W1, const float* __restrict__ W2,
                 const float* __restrict__ bn_gamma, const float* __restrict__ bn_beta,
                 const float* __restrict__ bn_mean, const float* __restrict__ bn_var,
                 const float* __restrict__ emb, const int* __restrict__ etype,
                 ushort* __restrict__ B1p, ushort* __restrict__ B2p,
                 float* __restrict__ sc, float* __restrict__ sh)
{
    int i = blockIdx.x * blockDim.x + threadIdx.x;
    if (i < 65536) {
        // B1 frag: i = ((ks*8 + ct)*64 + lane)*8 + j ; k = ks*32+(lane>>4)*8+j ; c = ct*16+(lane&15)
        int j = i & 7, lane = (i >> 3) & 63, ct = (i >> 9) & 7, ks = i >> 12;
        int k = ks * 32 + (lane >> 4) * 8 + j;
        int c = ct * 16 + (lane & 15);
        B1p[i] = f2bf(W1[k * HID + c]);
    } else if (i < 65536 + 8192) {
        int p = i - 65536;
        int j = p & 7, lane = (p >> 3) & 63, ct = (p >> 9) & 3, ks = p >> 11;
        int k = ks * 32 + (lane >> 4) * 8 + j;
        int c = ct * 16 + (lane & 15);
        B2p[p] = f2bf(W2[k * 64 + c]);
    } else if (i < 65536 + 8192 + HID) {
        int c = i - 65536 - 8192;
        float s = bn_gamma[c] * rsqrtf(bn_var[c] + 1e-5f);
        sc[c] = s;
        sh[c] = bn_beta[c] - bn_mean[c] * s + emb[etype[0] * HID + c];
    }
}

// ---------------- proj v3: P = h @ W1_half (+b1 on dst half) ----------------
// grid = NBLK blocks; block b does tiles {b, b+NBLK, b+2*NBLK} for each half.
__global__ __launch_bounds__(256)
void proj_kernel(const float* __restrict__ h_src, const float* __restrict__ h_dst,
                 const ushort* __restrict__ B1p, const float* __restrict__ b1,
                 ushort* __restrict__ Psrc, ushort* __restrict__ Pdst,
                 int n_nodes, int ntiles, int nblk)
{
    __shared__ ushort sA[ETILE * PS];     // 64 x 264 bf16 = 33792 B

    const int t    = threadIdx.x;
    const int lane = t & 63;
    const int w    = t >> 6;
    const int lr   = lane & 15;
    const int lq   = lane >> 4;

#pragma unroll 1
    for (int half = 0; half < 2; ++half) {
        const float* hp = half ? h_dst : h_src;
        ushort* Pp      = half ? Pdst : Psrc;

        // ---- B fragments for this half: 8 ksteps x 2 col-tiles, in registers ----
        bf16x8 bfr[8][2];
#pragma unroll
        for (int ks = 0; ks < 8; ++ks)
#pragma unroll
            for (int ctl = 0; ctl < 2; ++ctl)
                bfr[ks][ctl] = *reinterpret_cast<const bf16x8*>(
                    B1p + (size_t)(((half * 8 + ks) * 8 + 2 * w + ctl) * 64 + lane) * 8);

#pragma unroll 1
        for (int tile = blockIdx.x; tile < ntiles; tile += nblk) {
            const int nb = tile * 64;

            __syncthreads();   // prev tile's sA readers done

            // ---- stage full K: 64 rows x 256 cols, 4096 float4, 16/thread ----
#pragma unroll
            for (int i = 0; i < 16; ++i) {
                int f = t + i * 256;
                int e = f >> 6, q = f & 63;
                int row = nb + e;
                if (row >= n_nodes) row = n_nodes - 1;   // tail clamp (stores guarded)
                float4 v = *reinterpret_cast<const float4*>(
                    hp + (size_t)row * 256 + q * 4);
                ushort4 bv;
                bv.x = f2bf(v.x); bv.y = f2bf(v.y); bv.z = f2bf(v.z); bv.w = f2bf(v.w);
                *reinterpret_cast<ushort4*>(&sA[e * PS + q * 4]) = bv;
            }
            __syncthreads();

            // ---- MFMA: 8 K-slices x 4 row-tiles x 2 col-tiles, B from regs ----
            f32x4 acc[4][2];
#pragma unroll
            for (int rt = 0; rt < 4; ++rt)
#pragma unroll
                for (int c = 0; c < 2; ++c) acc[rt][c] = (f32x4)0.0f;

#pragma unroll
            for (int ks = 0; ks < 8; ++ks)
#pragma unroll
                for (int rt = 0; rt < 4; ++rt) {
                    bf16x8 af = *reinterpret_cast<const bf16x8*>(
                        &sA[(rt * 16 + lr) * PS + ks * 32 + lq * 8]);
                    acc[rt][0] = __builtin_amdgcn_mfma_f32_16x16x32_bf16(af, bfr[ks][0], acc[rt][0], 0, 0, 0);
                    acc[rt][1] = __builtin_amdgcn_mfma_f32_16x16x32_bf16(af, bfr[ks][1], acc[rt][1], 0, 0, 0);
                }

            __syncthreads();   // all sA readers done before X-tile overwrite

            // ---- epilogue: fold b1 on dst half; acc -> sA bf16 tile ----
#pragma unroll
            for (int ctl = 0; ctl < 2; ++ctl) {
                int c = (2 * w + ctl) * 16 + lr;
                float add = half ? b1[c] : 0.0f;
#pragma unroll
                for (int rt = 0; rt < 4; ++rt)
#pragma unroll
                    for (int r = 0; r < 4; ++r)
                        sA[(rt * 16 + lq * 4 + r) * PS + c] = f2bf(acc[rt][ctl][r] + add);
            }
            __syncthreads();

            // ---- cooperative coalesced store to P ----
#pragma unroll
            for (int i = 0; i < 4; ++i) {
                int f = t + i * 256;
                int e = f >> 4, q = f & 15;
                if (nb + e < n_nodes) {
                    u16x8 v = *reinterpret_cast<const u16x8*>(&sA[e * PS + q * 8]);
                    *reinterpret_cast<u16x8*>(Pp + (size_t)(nb + e) * 128 + q * 8) = v;
                }
            }
        }
    }
}

// ---------------- edge: coalesced gather + fuse + GEMM2/3 ----------------
__global__ __launch_bounds__(256)
void edge_kernel(const ushort* __restrict__ Psrc, const ushort* __restrict__ Pdst,
                 const int* __restrict__ src_nodes, const int* __restrict__ dst_nodes,
                 const float* __restrict__ sc, const float* __restrict__ sh,
                 const float* __restrict__ b2, const float* __restrict__ W3,
                 const float* __restrict__ b3, const ushort* __restrict__ B2p,
                 float* __restrict__ out, int n_edges)
{
    __shared__ ushort sX[ETILE * XS];
    __shared__ int s_s[ETILE], s_d[ETILE];

    const int t     = threadIdx.x;
    const int lane  = t & 63;
    const int w     = t >> 6;
    const int lr    = lane & 15;
    const int lq    = lane >> 4;
    const int ebase = blockIdx.x * ETILE;

    if (t < ETILE) {
        int e = ebase + t;
        s_s[t] = src_nodes[e < n_edges ? e : (n_edges - 1)];
    } else if (t < 2 * ETILE) {
        int e = ebase + t - ETILE;
        s_d[t - ETILE] = dst_nodes[e < n_edges ? e : (n_edges - 1)];
    }
    __syncthreads();

    // gather: 16 lanes per P row (256B contiguous segments)
    const int eg = w * 16 + lq;
    const int ch = lr;
    u16x8 gs[4], gd[4];
#pragma unroll
    for (int j = 0; j < 4; ++j)
        gs[j] = *reinterpret_cast<const u16x8*>(
            Psrc + (size_t)s_s[eg + j * 4] * 128 + ch * 8);
#pragma unroll
    for (int j = 0; j < 4; ++j)
        gd[j] = *reinterpret_cast<const u16x8*>(
            Pdst + (size_t)s_d[eg + j * 4] * 128 + ch * 8);
    asm volatile("" :: "v"(gs[0]), "v"(gs[1]), "v"(gs[2]), "v"(gs[3]),
                       "v"(gd[0]), "v"(gd[1]), "v"(gd[2]), "v"(gd[3]));

    // decode: relu(a+b) * sc + sh -> x (bf16) in LDS
    const int c0 = ch * 8;
    float4 sca = *reinterpret_cast<const float4*>(sc + c0);
    float4 scb = *reinterpret_cast<const float4*>(sc + c0 + 4);
    float4 sha = *reinterpret_cast<const float4*>(sh + c0);
    float4 shb = *reinterpret_cast<const float4*>(sh + c0 + 4);
    float ss[8] = {sca.x, sca.y, sca.z, sca.w, scb.x, scb.y, scb.z, scb.w};
    float zz[8] = {sha.x, sha.y, sha.z, sha.w, shb.x, shb.y, shb.z, shb.w};
#pragma unroll
    for (int j = 0; j < 4; ++j) {
        u16x8 xo;
#pragma unroll
        for (int i = 0; i < 8; ++i) {
            float v = bf2f((ushort)gs[j][i]) + bf2f((ushort)gd[j][i]);
            v = fmaxf(v, 0.0f);
            xo[i] = f2bf(fmaf(v, ss[i], zz[i]));
        }
        *reinterpret_cast<u16x8*>(&sX[(eg + j * 4) * XS + c0]) = xo;
    }
    __syncthreads();

    // -------- GEMM2 --------
    f32x4 acc2[4];
#pragma unroll
    for (int ct = 0; ct < 4; ++ct) acc2[ct] = (f32x4)0.0f;

#pragma unroll
    for (int ks = 0; ks < 4; ++ks) {
        bf16x8 af = *reinterpret_cast<const bf16x8*>(
            &sX[(w * 16 + lr) * XS + ks * 32 + lq * 8]);
#pragma unroll
        for (int ct = 0; ct < 4; ++ct) {
            bf16x8 bf = *reinterpret_cast<const bf16x8*>(
                B2p + (size_t)((ks * 4 + ct) * 64 + lane) * 8);
            acc2[ct] = __builtin_amdgcn_mfma_f32_16x16x32_bf16(af, bf, acc2[ct], 0, 0, 0);
        }
    }

    // -------- GEMM3 --------
    float w3v[4], b2v[4];
#pragma unroll
    for (int ct = 0; ct < 4; ++ct) {
        int c = ct * 16 + lr;
        w3v[ct] = W3[c];
        b2v[ct] = b2[c];
    }
#pragma unroll
    for (int r = 0; r < 4; ++r) {
        float sum = 0.0f;
#pragma unroll
        for (int ct = 0; ct < 4; ++ct)
            sum += fmaxf(acc2[ct][r] + b2v[ct], 0.0f) * w3v[ct];
        sum += __shfl_xor(sum, 1);
        sum += __shfl_xor(sum, 2);
        sum += __shfl_xor(sum, 4);
        sum += __shfl_xor(sum, 8);
        int eo = ebase + w * 16 + lq * 4 + r;
        if (lr == 0 && eo < n_edges) out[eo] = sum + b3[0];
    }
}

// ================= fallback: R10 champion fused path (97.7us) =================
__global__ __launch_bounds__(256, 3)
void edge_mlp_mfma(const float* __restrict__ h_src, const float* __restrict__ h_dst,
                   const int* __restrict__ src_nodes, const int* __restrict__ dst_nodes,
                   const ushort* __restrict__ B1p, const ushort* __restrict__ B2p,
                   const float* __restrict__ b1, const float* __restrict__ sc,
                   const float* __restrict__ sh, const float* __restrict__ b2,
                   const float* __restrict__ W3, const float* __restrict__ b3,
                   float* __restrict__ out, int n_edges)
{
    __shared__ ushort sA[2][ETILE * AS];
    __shared__ int s_src[ETILE], s_dst[ETILE];

    const int t    = threadIdx.x;
    const int lane = t & 63;
    const int w    = t >> 6;
    const int lr   = lane & 15;
    const int lq   = lane >> 4;
    const int ebase = blockIdx.x * ETILE;

    if (t < ETILE) {
        int e = ebase + t;
        s_src[t] = src_nodes[e < n_edges ? e : 0];
    } else if (t < 2 * ETILE) {
        int e = ebase + t - ETILE;
        s_dst[t - ETILE] = dst_nodes[e < n_edges ? e : 0];
    }

    f32x4 acc[4][2];
#pragma unroll
    for (int rt = 0; rt < 4; ++rt)
#pragma unroll
        for (int c = 0; c < 2; ++c) acc[rt][c] = (f32x4)0.0f;

    float4 rA[4], rB[4];
    bf16x8 Bf0[4], Bf1[4];

#define PHASE_BAR() do {                                                       \
        asm volatile("s_waitcnt lgkmcnt(0)" ::: "memory");                     \
        __builtin_amdgcn_s_barrier();                                          \
    } while (0)
#define PIN() __builtin_amdgcn_sched_barrier(0)

#define LOADC(kc, R) do {                                                      \
        const float* hp = ((kc) < 4) ? h_src : h_dst;                          \
        const int* sidx = ((kc) < 4) ? s_src : s_dst;                          \
        const int koff = ((kc) & 3) * 64;                                      \
        _Pragma("unroll")                                                      \
        for (int i = 0; i < 4; ++i) {                                          \
            int f = t + i * 256; int e = f >> 4; int q = f & 15;               \
            R[i] = *reinterpret_cast<const float4*>(                           \
                hp + (size_t)sidx[e] * 256 + koff + q * 4);                    \
        } } while (0)

#define BLOAD(kc, BR) do {                                                     \
        _Pragma("unroll")                                                      \
        for (int s = 0; s < 2; ++s)                                            \
        _Pragma("unroll")                                                      \
        for (int c = 0; c < 2; ++c)                                            \
            BR[s * 2 + c] = *reinterpret_cast<const bf16x8*>(                  \
                B1p + (size_t)((((kc) * 2 + s) * 8 + 2 * w + c) * 64 + lane) * 8); \
        } while (0)

#define STOREC(B, R) do {                                                      \
        _Pragma("unroll")                                                      \
        for (int i = 0; i < 4; ++i) {                                          \
            int f = t + i * 256; int e = f >> 4; int q = f & 15;               \
            ushort4 bv;                                                        \
            bv.x = f2bf(R[i].x); bv.y = f2bf(R[i].y);                          \
            bv.z = f2bf(R[i].z); bv.w = f2bf(R[i].w);                          \
            *reinterpret_cast<ushort4*>(&sA[B][e * AS + q * 4]) = bv;          \
        } } while (0)

#define COMPF(B, BR) do {                                                      \
        _Pragma("unroll")                                                      \
        for (int ks = 0; ks < 2; ++ks) {                                       \
            _Pragma("unroll")                                                  \
            for (int rt = 0; rt < 4; ++rt) {                                   \
                bf16x8 af = *reinterpret_cast<const bf16x8*>(                  \
                    &sA[B][(rt * 16 + lr) * AS + ks * 32 + lq * 8]);           \
                acc[rt][0] = __builtin_amdgcn_mfma_f32_16x16x32_bf16(af, BR[ks * 2 + 0], acc[rt][0], 0, 0, 0); \
                acc[rt][1] = __builtin_amdgcn_mfma_f32_16x16x32_bf16(af, BR[ks * 2 + 1], acc[rt][1], 0, 0, 0); \
            } } } while (0)

    __syncthreads();

    LOADC(0, rA);
    BLOAD(0, Bf0);
    STOREC(0, rA);
    LOADC(1, rB);
    BLOAD(1, Bf1);
    PHASE_BAR();

    LOADC(2, rA);  PIN();  COMPF(0, Bf0);  BLOAD(2, Bf0);  STOREC(1, rB);  PHASE_BAR();
    LOADC(3, rB);  PIN();  COMPF(1, Bf1);  BLOAD(3, Bf1);  STOREC(0, rA);  PHASE_BAR();
    LOADC(4, rA);  PIN();  COMPF(0, Bf0);  BLOAD(4, Bf0);  STOREC(1, rB);  PHASE_BAR();
    LOADC(5, rB);  PIN();  COMPF(1, Bf1);  BLOAD(5, Bf1);  STOREC(0, rA);  PHASE_BAR();
    LOADC(6, rA);  PIN();  COMPF(0, Bf0);  BLOAD(6, Bf0);  STOREC(1, rB);  PHASE_BAR();
    LOADC(7, rB);  PIN();  COMPF(1, Bf1);  BLOAD(7, Bf1);  STOREC(0, rA);  PHASE_BAR();
                           COMPF(0, Bf0);                  STOREC(1, rB);  PHASE_BAR();
                           COMPF(1, Bf1);

#undef LOADC
#undef BLOAD
#undef STOREC
#undef COMPF
#undef PIN
#undef PHASE_BAR

    __syncthreads();
    ushort* sX = &sA[0][0];
#pragma unroll
    for (int ctl = 0; ctl < 2; ++ctl) {
        int c = (2 * w + ctl) * 16 + lr;
        float bb = b1[c], s = sc[c], z = sh[c];
#pragma unroll
        for (int rt = 0; rt < 4; ++rt)
#pragma unroll
            for (int r = 0; r < 4; ++r) {
                float x = fmaxf(acc[rt][ctl][r] + bb, 0.0f);
                sX[(rt * 16 + lq * 4 + r) * XS + c] = f2bf(fmaf(x, s, z));
            }
    }
    __syncthreads();

    f32x4 acc2[4];
#pragma unroll
    for (int ct = 0; ct < 4; ++ct) acc2[ct] = (f32x4)0.0f;

#pragma unroll
    for (int ks = 0; ks < 4; ++ks) {
        bf16x8 af = *reinterpret_cast<const bf16x8*>(
            &sX[(w * 16 + lr) * XS + ks * 32 + lq * 8]);
#pragma unroll
        for (int ct = 0; ct < 4; ++ct) {
            bf16x8 bf = *reinterpret_cast<const bf16x8*>(
                B2p + (size_t)((ks * 4 + ct) * 64 + lane) * 8);
            acc2[ct] = __builtin_amdgcn_mfma_f32_16x16x32_bf16(af, bf, acc2[ct], 0, 0, 0);
        }
    }

    float w3v[4], b2v[4];
#pragma unroll
    for (int ct = 0; ct < 4; ++ct) {
        int c = ct * 16 + lr;
        w3v[ct] = W3[c];
        b2v[ct] = b2[c];
    }
#pragma unroll
    for (int r = 0; r < 4; ++r) {
        float sum = 0.0f;
#pragma unroll
        for (int ct = 0; ct < 4; ++ct)
            sum += fmaxf(acc2[ct][r] + b2v[ct], 0.0f) * w3v[ct];
        sum += __shfl_xor(sum, 1);
        sum += __shfl_xor(sum, 2);
        sum += __shfl_xor(sum, 4);
        sum += __shfl_xor(sum, 8);
        int e = ebase + w * 16 + lq * 4 + r;
        if (lr == 0 && e < n_edges) out[e] = sum + b3[0];
    }
}

extern "C" void kernel_launch(void* const* d_in, const int* in_sizes, int n_in,
                              void* d_out, int out_size, void* d_ws, size_t ws_size,
                              hipStream_t stream) {
    const float* h_src     = (const float*)d_in[0];
    const float* h_dst     = (const float*)d_in[1];
    const int*   src_nodes = (const int*)d_in[2];
    const int*   dst_nodes = (const int*)d_in[3];
    const int*   etype     = (const int*)d_in[4];
    const float* W1        = (const float*)d_in[5];
    const float* b1        = (const float*)d_in[6];
    const float* bn_gamma  = (const float*)d_in[7];
    const float* bn_beta   = (const float*)d_in[8];
    const float* bn_mean   = (const float*)d_in[9];
    const float* bn_var    = (const float*)d_in[10];
    const float* emb       = (const float*)d_in[11];
    const float* W2        = (const float*)d_in[12];
    const float* b2        = (const float*)d_in[13];
    const float* W3        = (const float*)d_in[14];
    const float* b3        = (const float*)d_in[15];

    const int n_edges = in_sizes[2];
    const int n_nodes = in_sizes[0] / 256;

    // d_ws layout: B1p[65536 u16] | B2p[8192 u16] | sc[128] | sh[128] | Psrc | Pdst
    ushort* B1p = (ushort*)d_ws;
    ushort* B2p = B1p + 65536;
    float*  scp = (float*)(B2p + 8192);
    float*  shp = scp + HID;
    const size_t wbytes = (size_t)(65536 + 8192) * 2 + 256 * 4;   // 148480 B
    const size_t pbytes = (size_t)n_nodes * HID * 2;              // per P array
    ushort* Psrc = (ushort*)((char*)d_ws + wbytes);
    ushort* Pdst = Psrc + (size_t)n_nodes * HID;

    prep_kernel<<<(65536 + 8192 + HID + 255) / 256, 256, 0, stream>>>(
        W1, W2, bn_gamma, bn_beta, bn_mean, bn_var, emb, etype, B1p, B2p, scp, shp);

    const int egrid = (n_edges + ETILE - 1) / ETILE;

    if (ws_size >= wbytes + 2 * pbytes) {
        const int ntiles = (n_nodes + 63) / 64;
        const int nblk   = (ntiles + 2) / 3;     // 3 tiles/half per block, exact cover
        proj_kernel<<<nblk, 256, 0, stream>>>(h_src, h_dst, B1p, b1,
                                              Psrc, Pdst, n_nodes, ntiles, nblk);
        edge_kernel<<<egrid, 256, 0, stream>>>(Psrc, Pdst, src_nodes, dst_nodes,
                                               scp, shp, b2, W3, b3, B2p,
                                               (float*)d_out, n_edges);
    } else {
        edge_mlp_mfma<<<egrid, 256, 0, stream>>>(h_src, h_dst, src_nodes, dst_nodes,
                                                 B1p, B2p, b1, scp, shp, b2, W3, b3,
                                                 (float*)d_out, n_edges);
    }
}